// Round 5
// baseline (535.250 us; speedup 1.0000x reference)
//
#include <hip/hip_runtime.h>
#include <stdint.h>

// Fused single-kernel top-k (k = 10% of N) by value over flat fp32.
// Round-5: LDS diet -> 100% occupancy. Round-4 post-mortem: counters showed
// latency-bound (Occupancy 45%, VALUBusy 14.5%, HBM 22%) with LDS (34 KB)
// capping us at 4 blocks/CU. This version fits in <20 KB LDS -> 8 blocks/CU
// (32 waves/CU), grid 2048.
//   - pass 1: 11-bit hist (2048 bins, ONE 8 KB LDS copy)
//   - radix split 11 + 11 + 10 bits
//   - stage cap 1280/block (grid 2048 -> mean ~360 cands/block; fallback kept)
//   - phase B: uniform full-quad NT stores (candidate lanes = 0);
//     owning block rewrites its own candidate dwords in D/E -> still exactly
//     one writer per dword (no cross-XCD dirty-line races, no fences needed)
// Hierarchical fenceless grid barrier (32 groups of 64 blocks) as round 4.
// Phases (common path, 3 barriers):
//   A: 11-bit hist -> device atomics                 [read x]
//   (1) | scanA -> b1,krem
//   B: full-quad NT scatter + stage own candidates + C1 hist(b20..10)
//   (2) | scanB -> b2,krem2
//   C2: hist(b9..0) of own candidates
//   (3) | scanC -> t_u, need_eq, ceq
//   D: owner writes own candidates > t_u (and ties if need_eq==ceq)
//   [rare ties: (4) + owner-ranked tie writes; rare overflow: full rescan]

#define BLK       256
#define MAXGRID   2048
#define NB1       2048   // top 11 bits (shift 21)
#define NC1       2048   // bits 20..10
#define NC2       1024   // bits 9..0
#define STAGE_CAP 1280   // per-block candidate cap
#define EQ_CAP    65536
#define GRP_SHIFT 6      // 64 blocks per barrier group
#define LSTRIDE   64     // dwords (256 B) between barrier lines

typedef float vf4 __attribute__((ext_vector_type(4)));

__device__ __forceinline__ unsigned f2u(float x) {
    unsigned b = __float_as_uint(x);
    return (b & 0x80000000u) ? ~b : (b | 0x80000000u);
}
__device__ __forceinline__ float u2f(unsigned u) {
    return __uint_as_float((u & 0x80000000u) ? (u & 0x7FFFFFFFu) : ~u);
}
__device__ __forceinline__ unsigned cload(const unsigned* p) {
    return __hip_atomic_load(p, __ATOMIC_RELAXED, __HIP_MEMORY_SCOPE_AGENT);
}
__device__ __forceinline__ void cstore(unsigned* p, unsigned v) {
    __hip_atomic_store(p, v, __ATOMIC_RELAXED, __HIP_MEMORY_SCOPE_AGENT);
}

// Hierarchical fenceless grid barrier. Monotonic epoch counters, no reset.
// __syncthreads() drains vmcnt before arrival (release); cross-block data is
// all device-scope-atomic-written (L3) and read back with sc1 loads.
__device__ __forceinline__ void gsync(unsigned* bw, unsigned ep, unsigned nbk) {
    __syncthreads();
    if (threadIdx.x == 0) {
        const unsigned g  = (unsigned)blockIdx.x >> GRP_SHIFT;
        const unsigned ng = (nbk + ((1u << GRP_SHIFT) - 1u)) >> GRP_SHIFT;
        unsigned* arr = bw;                        // arr[g*LSTRIDE], g < 32
        unsigned* gar = bw + 2048;                 // own line
        unsigned* rel = bw + 2112;                 // rel[g*LSTRIDE]
        unsigned grp0 = g << GRP_SHIFT;
        unsigned cnt_g = nbk - grp0;
        if (cnt_g > (1u << GRP_SHIFT)) cnt_g = (1u << GRP_SHIFT);
        unsigned old = __hip_atomic_fetch_add(&arr[g * LSTRIDE], 1u,
                                              __ATOMIC_RELAXED, __HIP_MEMORY_SCOPE_AGENT);
        if (old == ep * cnt_g - 1u) {              // last arrival in group
            unsigned og = __hip_atomic_fetch_add(gar, 1u,
                                                 __ATOMIC_RELAXED, __HIP_MEMORY_SCOPE_AGENT);
            if (og == ep * ng - 1u) {              // last group: release all
                for (unsigned i = 0; i < ng; ++i)
                    cstore(&rel[i * LSTRIDE], ep);
            }
        }
        unsigned spins = 0u;
        while (cload(&rel[g * LSTRIDE]) < ep) {
            __builtin_amdgcn_s_sleep(8);           // ~0.2 us polls
            if (++spins > 3000000u) break;         // failsafe
        }
    }
    __syncthreads();
}

__device__ __forceinline__ unsigned block_exscan256(unsigned v,
                                                    volatile unsigned* lds,
                                                    int tid)
{
    lds[tid] = v;
    __syncthreads();
    for (int off = 1; off < 256; off <<= 1) {
        unsigned t = (tid >= off) ? lds[tid - off] : 0u;
        __syncthreads();
        lds[tid] += t;
        __syncthreads();
    }
    unsigned incl = lds[tid];
    return incl - v;
}

// Descending scan over NB bins (device hist read with sc1 loads).
// Writes sb[0]=bin, sb[1]=k-cum (remaining), sb[2]=bin count.
template<int NB, int PT>
__device__ void scan_desc(const unsigned* h, unsigned kin,
                          volatile unsigned* slds, unsigned* sb, int tid)
{
    unsigned loc[PT], partial = 0u;
#pragma unroll
    for (int i = 0; i < PT; ++i) {
        loc[i] = cload(&h[NB - 1 - (tid * PT + i)]);
        partial += loc[i];
    }
    unsigned cum = block_exscan256(partial, slds, tid);
#pragma unroll
    for (int i = 0; i < PT; ++i) {
        unsigned c = loc[i];
        if (cum < kin && cum + c >= kin) {
            sb[0] = (unsigned)(NB - 1 - (tid * PT + i));
            sb[1] = kin - cum;
            sb[2] = c;
        }
        cum += c;
    }
    __syncthreads();
}

__global__ void __launch_bounds__(BLK, 8)
topk_fused(const float* __restrict__ x, float* __restrict__ out,
           long long N, int n4, unsigned k,
           unsigned* __restrict__ sc, unsigned* __restrict__ bw,
           unsigned* __restrict__ hist_a, unsigned* __restrict__ hist_b,
           unsigned* __restrict__ hist_c, unsigned* __restrict__ hist_b2,
           unsigned* __restrict__ hist_c2, unsigned* __restrict__ eq_list)
{
    // 18 KB time-shared: A = hist[2048]; B..E = su[1280]|si[1280]|chist[2048]
    __shared__ unsigned lh[2 * STAGE_CAP + NC1];
    __shared__ unsigned slds[BLK];
    __shared__ unsigned sb[8];

    const int tid = threadIdx.x;
    const int bid = blockIdx.x;
    const unsigned nbk = gridDim.x;
    const int stride = (int)nbk * BLK;
    unsigned ep = 0;

    const float4* x4 = (const float4*)x;
    const long long t0 = (long long)n4 * 4;
    const int ntail = (int)(N - t0);

    // ---------------- A: 11-bit histogram (single LDS copy) ----------------
    for (int i = tid; i < NB1; i += BLK) lh[i] = 0u;
    __syncthreads();
    for (int i = bid * BLK + tid; i < n4; i += stride) {
        float4 v = x4[i];
        atomicAdd(&lh[f2u(v.x) >> 21], 1u);
        atomicAdd(&lh[f2u(v.y) >> 21], 1u);
        atomicAdd(&lh[f2u(v.z) >> 21], 1u);
        atomicAdd(&lh[f2u(v.w) >> 21], 1u);
    }
    if (bid == 0 && tid < ntail) atomicAdd(&lh[f2u(x[t0 + tid]) >> 21], 1u);
    __syncthreads();
    for (int i = tid; i < NB1; i += BLK) {
        unsigned s = lh[i];
        if (s) atomicAdd(&hist_a[i], s);     // device scope -> L3
    }
    gsync(bw, ++ep, nbk);                    // (1) hist_a complete

    scan_desc<NB1, NB1 / BLK>(hist_a, k, slds, sb, tid);
    const unsigned b1 = sb[0], krem = sb[1];
    __syncthreads();

    // ------- B: full-quad NT scatter + stage own candidates + C1 -------
    if (tid == 0) sb[3] = 0u;
    __syncthreads();
    unsigned* su = lh;                  // candidate sortable-u32
    unsigned* si = lh + STAGE_CAP;      // candidate flat index
    unsigned* chist = lh + 2 * STAGE_CAP;  // 2048 dwords
    auto stage = [&](unsigned u, unsigned idxv) {
        unsigned p = atomicAdd(&sb[3], 1u);
        if (p < STAGE_CAP) { su[p] = u; si[p] = idxv; }
        else cstore(&sc[7], 1u);        // overflow -> global flag
    };
    for (int i = bid * BLK + tid; i < n4; i += stride) {
        float4 v = x4[i];
        unsigned u0 = f2u(v.x), u1 = f2u(v.y), u2 = f2u(v.z), u3 = f2u(v.w);
        vf4 o;
        o.x = ((u0 >> 21) > b1) ? v.x : 0.0f;
        o.y = ((u1 >> 21) > b1) ? v.y : 0.0f;
        o.z = ((u2 >> 21) > b1) ? v.z : 0.0f;
        o.w = ((u3 >> 21) > b1) ? v.w : 0.0f;
        __builtin_nontemporal_store(o, (vf4*)out + i);   // candidates get 0 now
        if (((u0 >> 21) == b1) | ((u1 >> 21) == b1) |
            ((u2 >> 21) == b1) | ((u3 >> 21) == b1)) {
            unsigned base = (unsigned)i * 4u;
            if ((u0 >> 21) == b1) stage(u0, base + 0u);
            if ((u1 >> 21) == b1) stage(u1, base + 1u);
            if ((u2 >> 21) == b1) stage(u2, base + 2u);
            if ((u3 >> 21) == b1) stage(u3, base + 3u);
        }
    }
    if (bid == 0 && tid < ntail) {
        long long idx = t0 + tid;
        float v = x[idx];
        unsigned u = f2u(v);
        out[idx] = ((u >> 21) > b1) ? v : 0.0f;
        if ((u >> 21) == b1) stage(u, (unsigned)idx);
    }
    __syncthreads();
    const unsigned mycnt0 = sb[3];
    const unsigned mycnt = (mycnt0 > STAGE_CAP) ? STAGE_CAP : mycnt0;
    // C1 on own candidates (hist_b garbage if any block overflowed; the
    // fallback below then rebuilds into hist_b2).
    for (int i = tid; i < NC1; i += BLK) chist[i] = 0u;
    __syncthreads();
    for (unsigned j = (unsigned)tid; j < mycnt; j += BLK)
        atomicAdd(&chist[(su[j] >> 10) & (NC1 - 1u)], 1u);
    __syncthreads();
    for (int i = tid; i < NC1; i += BLK) {
        unsigned s = chist[i];
        if (s) atomicAdd(&hist_b[i], s);
    }
    gsync(bw, ++ep, nbk);                    // (2) hist_b + ovf flag complete

    const bool ovf = (cload(&sc[7]) != 0u);

    if (!ovf) {
        // ---------------- common path ----------------
        scan_desc<NC1, NC1 / BLK>(hist_b, krem, slds, sb, tid);
        const unsigned b2 = sb[0], krem2 = sb[1];
        __syncthreads();

        // C2: bits 9..0 of own candidates, filtered
        for (int i = tid; i < NC2; i += BLK) chist[i] = 0u;
        __syncthreads();
        for (unsigned j = (unsigned)tid; j < mycnt; j += BLK) {
            unsigned u = su[j];
            if (((u >> 10) & (NC1 - 1u)) == b2) atomicAdd(&chist[u & (NC2 - 1u)], 1u);
        }
        __syncthreads();
        for (int i = tid; i < NC2; i += BLK) {
            unsigned s = chist[i];
            if (s) atomicAdd(&hist_c[i], s);
        }
        gsync(bw, ++ep, nbk);                // (3) hist_c complete

        scan_desc<NC2, NC2 / BLK>(hist_c, krem2, slds, sb, tid);
        const unsigned b3 = sb[0], needeq = sb[1], ceq = sb[2];
        const unsigned tu = (b1 << 21) | (b2 << 10) | b3;
        const bool allties = (needeq == ceq);   // uniform across all blocks

        // D: owner writes own candidates (B already wrote 0 there)
        for (unsigned j = (unsigned)tid; j < mycnt; j += BLK) {
            unsigned u = su[j];
            if (u > tu)                  out[si[j]] = u2f(u);
            else if (u == tu) {
                if (allties)             out[si[j]] = u2f(u);
                else { unsigned q = atomicAdd(&sc[5], 1u);
                       if (q < EQ_CAP) cstore(&eq_list[q], si[j]); }
            }
        }
        if (!allties) {                       // rare: stable tie-break
            gsync(bw, ++ep, nbk);             // (4) eq_list complete
            unsigned m = cload(&sc[5]); if (m > EQ_CAP) m = EQ_CAP;
            float f = u2f(tu);
            for (unsigned j = (unsigned)tid; j < mycnt; j += BLK) {
                unsigned u = su[j];
                if (u != tu) continue;
                unsigned idxv = si[j];
                unsigned cnt = 0u;            // rank own tie vs global list
                for (unsigned l = 0; l < m; ++l)
                    cnt += (cload(&eq_list[l]) < idxv) ? 1u : 0u;
                if (cnt < needeq) out[idxv] = f;   // losers stay 0 (B wrote it)
            }
        }
    } else {
        // ------------- overflow fallback: full-rescan radix -------------
        for (int i = tid; i < NC1; i += BLK) chist[i] = 0u;
        __syncthreads();
        for (int i = bid * BLK + tid; i < n4; i += stride) {
            float4 v = x4[i];
            unsigned u;
            u = f2u(v.x); if ((u >> 21) == b1) atomicAdd(&chist[(u >> 10) & (NC1 - 1u)], 1u);
            u = f2u(v.y); if ((u >> 21) == b1) atomicAdd(&chist[(u >> 10) & (NC1 - 1u)], 1u);
            u = f2u(v.z); if ((u >> 21) == b1) atomicAdd(&chist[(u >> 10) & (NC1 - 1u)], 1u);
            u = f2u(v.w); if ((u >> 21) == b1) atomicAdd(&chist[(u >> 10) & (NC1 - 1u)], 1u);
        }
        if (bid == 0 && tid < ntail) {
            unsigned u = f2u(x[t0 + tid]);
            if ((u >> 21) == b1) atomicAdd(&chist[(u >> 10) & (NC1 - 1u)], 1u);
        }
        __syncthreads();
        for (int i = tid; i < NC1; i += BLK) {
            unsigned s = chist[i];
            if (s) atomicAdd(&hist_b2[i], s);
        }
        gsync(bw, ++ep, nbk);
        scan_desc<NC1, NC1 / BLK>(hist_b2, krem, slds, sb, tid);
        const unsigned b2 = sb[0], krem2 = sb[1];
        __syncthreads();

        for (int i = tid; i < NC2; i += BLK) chist[i] = 0u;
        __syncthreads();
        for (int i = bid * BLK + tid; i < n4; i += stride) {
            float4 v = x4[i];
            unsigned u;
            u = f2u(v.x); if ((u >> 21) == b1 && ((u >> 10) & (NC1 - 1u)) == b2) atomicAdd(&chist[u & (NC2 - 1u)], 1u);
            u = f2u(v.y); if ((u >> 21) == b1 && ((u >> 10) & (NC1 - 1u)) == b2) atomicAdd(&chist[u & (NC2 - 1u)], 1u);
            u = f2u(v.z); if ((u >> 21) == b1 && ((u >> 10) & (NC1 - 1u)) == b2) atomicAdd(&chist[u & (NC2 - 1u)], 1u);
            u = f2u(v.w); if ((u >> 21) == b1 && ((u >> 10) & (NC1 - 1u)) == b2) atomicAdd(&chist[u & (NC2 - 1u)], 1u);
        }
        if (bid == 0 && tid < ntail) {
            unsigned u = f2u(x[t0 + tid]);
            if ((u >> 21) == b1 && ((u >> 10) & (NC1 - 1u)) == b2) atomicAdd(&chist[u & (NC2 - 1u)], 1u);
        }
        __syncthreads();
        for (int i = tid; i < NC2; i += BLK) {
            unsigned s = chist[i];
            if (s) atomicAdd(&hist_c2[i], s);
        }
        gsync(bw, ++ep, nbk);
        scan_desc<NC2, NC2 / BLK>(hist_c2, krem2, slds, sb, tid);
        const unsigned b3 = sb[0], needeq = sb[1], ceq = sb[2];
        const unsigned tu = (b1 << 21) | (b2 << 10) | b3;
        const bool allties = (needeq == ceq);

        // D (fallback): same quad partition as B -> same owner per dword
        for (int i = bid * BLK + tid; i < n4; i += stride) {
            float4 v = x4[i];
            unsigned base = (unsigned)i * 4u;
            unsigned uu[4] = { f2u(v.x), f2u(v.y), f2u(v.z), f2u(v.w) };
#pragma unroll
            for (int l = 0; l < 4; ++l) {
                unsigned u = uu[l];
                if ((u >> 21) != b1) continue;
                if (u > tu)                  out[base + l] = u2f(u);
                else if (u == tu) {
                    if (allties)             out[base + l] = u2f(u);
                    else { unsigned q = atomicAdd(&sc[5], 1u);
                           if (q < EQ_CAP) cstore(&eq_list[q], base + (unsigned)l); }
                }
            }
        }
        if (bid == 0 && tid < ntail) {
            long long idx = t0 + tid;
            unsigned u = f2u(x[idx]);
            if ((u >> 21) == b1) {
                if (u > tu)                  out[idx] = u2f(u);
                else if (u == tu) {
                    if (allties)             out[idx] = u2f(u);
                    else { unsigned q = atomicAdd(&sc[5], 1u);
                           if (q < EQ_CAP) cstore(&eq_list[q], (unsigned)idx); }
                }
            }
        }
        if (!allties) {
            gsync(bw, ++ep, nbk);
            unsigned m = cload(&sc[5]); if (m > EQ_CAP) m = EQ_CAP;
            float f = u2f(tu);
            for (int i = bid * BLK + tid; i < n4; i += stride) {
                float4 v = x4[i];
                unsigned base = (unsigned)i * 4u;
                unsigned uu[4] = { f2u(v.x), f2u(v.y), f2u(v.z), f2u(v.w) };
#pragma unroll
                for (int l = 0; l < 4; ++l) {
                    if (uu[l] != tu) continue;
                    unsigned idxv = base + (unsigned)l;
                    unsigned cnt = 0u;
                    for (unsigned q = 0; q < m; ++q)
                        cnt += (cload(&eq_list[q]) < idxv) ? 1u : 0u;
                    if (cnt < needeq) out[idxv] = f;
                }
            }
            if (bid == 0 && tid < ntail) {
                long long idx = t0 + tid;
                if (f2u(x[idx]) == tu) {
                    unsigned cnt = 0u;
                    for (unsigned q = 0; q < m; ++q)
                        cnt += (cload(&eq_list[q]) < (unsigned)idx) ? 1u : 0u;
                    if (cnt < needeq) out[idx] = f;
                }
            }
        }
    }
}

extern "C" void kernel_launch(void* const* d_in, const int* in_sizes, int n_in,
                              void* d_out, int out_size, void* d_ws, size_t ws_size,
                              hipStream_t stream) {
    const float* x = (const float*)d_in[0];
    float* out = (float*)d_out;
    long long N = (long long)in_sizes[0];
    int n4 = (int)(N >> 2);
    unsigned k = (unsigned)((double)N * 0.1);
    if (k == 0u) k = 1u;

    uint8_t* w = (uint8_t*)d_ws;
    unsigned* sc      = (unsigned*)(w);                  // 256 B scalars
    unsigned* bw      = (unsigned*)(w + 256);            // 20 KB barrier lines
    unsigned* hist_a  = (unsigned*)(w + 256 + 20480);    // 8 KB
    unsigned* hist_b  = hist_a + NB1;                    // 8 KB
    unsigned* hist_c  = hist_b + NC1;                    // 4 KB
    unsigned* hist_b2 = hist_c + NC2;                    // 8 KB
    unsigned* hist_c2 = hist_b2 + NC1;                   // 4 KB
    unsigned* eq_list = hist_c2 + NC2;                   // 256 KB (not zeroed)
    const size_t zbytes = 256 + 20480 +
        (size_t)(NB1 + NC1 + NC2 + NC1 + NC2) * sizeof(unsigned);

    // Grid sized for guaranteed co-residency (grid barrier inside).
    static int g_grid = 0;
    if (g_grid == 0) {
        int nb = 0;
        if (hipOccupancyMaxActiveBlocksPerMultiprocessor(&nb, (const void*)topk_fused,
                                                         BLK, 0) != hipSuccess || nb < 1)
            nb = 8;   // ~19.5 KB LDS, <=64 VGPR -> 8 blocks/CU
        int dev = 0; (void)hipGetDevice(&dev);
        int ncu = 0;
        if (hipDeviceGetAttribute(&ncu, hipDeviceAttributeMultiprocessorCount, dev) != hipSuccess || ncu < 1)
            ncu = 256;
        long long g = (long long)nb * (long long)ncu;
        if (g > MAXGRID) g = MAXGRID;
        if (g < 1) g = 1;
        g_grid = (int)g;
    }

    (void)hipMemsetAsync(w, 0, zbytes, stream);   // scalars + barrier + hists
    hipLaunchKernelGGL(topk_fused, dim3(g_grid), dim3(BLK), 0, stream,
                       x, out, N, n4, k, sc, bw,
                       hist_a, hist_b, hist_c, hist_b2, hist_c2, eq_list);
}

// Round 7
// 378.634 us; speedup vs baseline: 1.4136x; 1.4136x over previous
//
#include <hip/hip_runtime.h>
#include <stdint.h>
#include <math.h>

// Fused single-kernel top-k (k = 10% of N) by value over flat fp32.
// Round-7: identical to round-6 design (sampling replaces the full histogram
// pass) with the compile fix: ext_vector elements are not addressable, so
// classify() returns its output by value.
//   r5 post-mortem: occupancy 45->91% made it SLOWER (203 vs 176us) -> not
//   latency-bound; the full-N hist pass (134MB read + 134M hot-bin LDS
//   atomics + 2048-way serialized hist flush) was structural overhead.
// Structure (common path, 4 barriers, grid 1024):
//   S1: blocks 0..255 sample 1/16 of x (contiguous 4KB runs), 11-bit LDS
//       hist -> channel-spread replicated global counters (256-way flush)
//   (1) scanS1 (all blocks, redundant) -> window of 4 top bins (2^23 range)
//   S2: sample re-read (L2-hot), hist at 2^12 granularity in window
//   (2) scanS2 twice with +-8sigma margins -> band [lo,hi), t_u in band whp
//   STREAM: one full pass: u>=hi -> out=v (count n_hi); u in [lo,hi) ->
//       out=0 + stage (u,idx) in block-local LDS; else out=0. NT quad
//       stores. Then C1 counts (replicated global, direct) of own cands.
//   (3) validity check (EXACT: n_hi<=k<=n_hi+n_cand, no overflow) ->
//       scanC1 -> C2 direct counts -> (4) -> scanC2 -> t_u, need_eq
//   D: owner rewrites own candidates (same block wrote the line -> single
//      XCD per 64B line, no fences). Rare ties: (5) + owner-ranked writes.
//   Sampling failure/overflow -> full 3-pass radix fallback (correct, slow).
// Fenceless hierarchical grid barrier as rounds 4/5.

#define BLK       256
#define MAXGRID   1024
#define SAMPB     256     // sampling blocks
#define REPL      4       // global counter replicas
#define CSTR      16      // dwords between counters (64 B -> channel spread)
#define NSB       2048    // sample hist bins
#define NC2       4096    // C2 bins (low 12 bits of band offset)
#define STAGE_CAP 768     // per-block candidate cap (mean ~120)
#define EQ_CAP    65536
#define GRP_SHIFT 6
#define LSTRIDE   64
#define SENT      0xFFFFFFFFu

typedef float vf4 __attribute__((ext_vector_type(4)));

__device__ __forceinline__ unsigned f2u(float x) {
    unsigned b = __float_as_uint(x);
    return (b & 0x80000000u) ? ~b : (b | 0x80000000u);
}
__device__ __forceinline__ float u2f(unsigned u) {
    return __uint_as_float((u & 0x80000000u) ? (u & 0x7FFFFFFFu) : ~u);
}
__device__ __forceinline__ unsigned cload(const unsigned* p) {
    return __hip_atomic_load(p, __ATOMIC_RELAXED, __HIP_MEMORY_SCOPE_AGENT);
}
__device__ __forceinline__ void cstore(unsigned* p, unsigned v) {
    __hip_atomic_store(p, v, __ATOMIC_RELAXED, __HIP_MEMORY_SCOPE_AGENT);
}

__device__ __forceinline__ void gsync(unsigned* bw, unsigned ep, unsigned nbk) {
    __syncthreads();
    if (threadIdx.x == 0) {
        const unsigned g  = (unsigned)blockIdx.x >> GRP_SHIFT;
        const unsigned ng = (nbk + ((1u << GRP_SHIFT) - 1u)) >> GRP_SHIFT;
        unsigned* arr = bw;
        unsigned* gar = bw + 1024;
        unsigned* rel = bw + 1088;
        unsigned grp0 = g << GRP_SHIFT;
        unsigned cnt_g = nbk - grp0;
        if (cnt_g > (1u << GRP_SHIFT)) cnt_g = (1u << GRP_SHIFT);
        unsigned old = __hip_atomic_fetch_add(&arr[g * LSTRIDE], 1u,
                                              __ATOMIC_RELAXED, __HIP_MEMORY_SCOPE_AGENT);
        if (old == ep * cnt_g - 1u) {
            unsigned og = __hip_atomic_fetch_add(gar, 1u,
                                                 __ATOMIC_RELAXED, __HIP_MEMORY_SCOPE_AGENT);
            if (og == ep * ng - 1u)
                for (unsigned i = 0; i < ng; ++i) cstore(&rel[i * LSTRIDE], ep);
        }
        unsigned spins = 0u;
        while (cload(&rel[g * LSTRIDE]) < ep) {
            __builtin_amdgcn_s_sleep(8);
            if (++spins > 3000000u) break;
        }
    }
    __syncthreads();
}

__device__ __forceinline__ unsigned block_exscan256(unsigned v,
                                                    volatile unsigned* lds,
                                                    int tid)
{
    lds[tid] = v;
    __syncthreads();
    for (int off = 1; off < 256; off <<= 1) {
        unsigned t = (tid >= off) ? lds[tid - off] : 0u;
        __syncthreads();
        lds[tid] += t;
        __syncthreads();
    }
    unsigned incl = lds[tid];
    return incl - v;
}

__device__ __forceinline__ unsigned block_reduce_sum(unsigned v,
                                                     volatile unsigned* lds,
                                                     int tid)
{
    lds[tid] = v;
    __syncthreads();
    for (int off = 128; off; off >>= 1) {
        if (tid < off) lds[tid] += lds[tid + off];
        __syncthreads();
    }
    unsigned r = lds[0];
    __syncthreads();
    return r;
}

// Descending scan over NB bins; counter value = sum of R replicas at
// stride STR dwords. sb[0]=bin (SENT if no crossing), sb[1]=kin-cum, sb[2]=count.
template<int NB, int PT, int R, int STR>
__device__ void scan_desc(const unsigned* h, unsigned kin,
                          volatile unsigned* slds, unsigned* sb, int tid)
{
    unsigned loc[PT], partial = 0u;
#pragma unroll
    for (int i = 0; i < PT; ++i) {
        unsigned bin = (unsigned)(NB - 1 - (tid * PT + i));
        unsigned s = 0u;
#pragma unroll
        for (int r = 0; r < R; ++r) s += cload(&h[(bin * R + r) * STR]);
        loc[i] = s; partial += s;
    }
    if (tid == 0) sb[0] = SENT;
    unsigned cum = block_exscan256(partial, slds, tid);
#pragma unroll
    for (int i = 0; i < PT; ++i) {
        unsigned c = loc[i];
        if (cum < kin && cum + c >= kin) {
            sb[0] = (unsigned)(NB - 1 - (tid * PT + i));
            sb[1] = kin - cum;
            sb[2] = c;
        }
        cum += c;
    }
    __syncthreads();
}

__global__ void __launch_bounds__(BLK, 4)
topk_fused(const float* __restrict__ x, float* __restrict__ out,
           long long N, int n4, unsigned k,
           unsigned nchunks, unsigned ksamp, unsigned delta,
           unsigned* __restrict__ sc, unsigned* __restrict__ bw,
           unsigned* __restrict__ hS1, unsigned* __restrict__ hS2,
           unsigned* __restrict__ hC1, unsigned* __restrict__ hC2,
           unsigned* __restrict__ hF1, unsigned* __restrict__ hF2,
           unsigned* __restrict__ hF3, unsigned* __restrict__ eq_list)
{
    __shared__ unsigned lh[NSB];      // 8 KB: sample hists / F hists / stage
    __shared__ unsigned slds[BLK];
    __shared__ unsigned sb[8];

    const int tid = threadIdx.x;
    const int bid = blockIdx.x;
    const unsigned nbk = gridDim.x;
    const int stride = (int)nbk * BLK;
    unsigned ep = 0;

    const float4* x4 = (const float4*)x;
    const long long t0 = (long long)n4 * 4;
    const int ntail = (int)(N - t0);

    // ---------------- S1: sample 11-bit histogram ----------------
    for (int i = tid; i < NSB; i += BLK) lh[i] = 0u;
    __syncthreads();
    if (bid < SAMPB) {
        for (unsigned c = (unsigned)bid; c < nchunks; c += SAMPB) {
            float4 v = x4[(size_t)c * 4096 + (unsigned)tid];
            atomicAdd(&lh[f2u(v.x) >> 21], 1u);
            atomicAdd(&lh[f2u(v.y) >> 21], 1u);
            atomicAdd(&lh[f2u(v.z) >> 21], 1u);
            atomicAdd(&lh[f2u(v.w) >> 21], 1u);
        }
    }
    __syncthreads();
    if (bid < SAMPB) {
        unsigned r = (unsigned)bid & (REPL - 1);
        for (int i = tid; i < NSB; i += BLK) {
            unsigned s = lh[i];
            if (s) atomicAdd(&hS1[((unsigned)i * REPL + r) * CSTR], s);
        }
    }
    gsync(bw, ++ep, nbk);                 // (1)

    scan_desc<NSB, NSB / BLK, REPL, CSTR>(hS1, ksamp, slds, sb, tid);
    unsigned s1bin = sb[0];
    bool bad = (s1bin == SENT);
    unsigned wb = 0u;
    if (!bad) { wb = (s1bin > 0u) ? s1bin - 1u : 0u; if (wb > NSB - 4u) wb = NSB - 4u; }
    const unsigned wbase = wb << 21;
    const unsigned wtop  = wbase + (1u << 23);
    // samples strictly above the window
    unsigned part = 0u;
    for (int i = tid; i < NSB; i += BLK) {
        if ((unsigned)i > wb + 3u) {
#pragma unroll
            for (int r = 0; r < REPL; ++r)
                part += cload(&hS1[((unsigned)i * REPL + r) * CSTR]);
        }
    }
    const unsigned aw = block_reduce_sum(part, slds, tid);

    // ---------------- S2: refine within window (2^12 granularity) ---------
    for (int i = tid; i < NSB; i += BLK) lh[i] = 0u;
    __syncthreads();
    if (bid < SAMPB && !bad) {
        for (unsigned c = (unsigned)bid; c < nchunks; c += SAMPB) {
            float4 v = x4[(size_t)c * 4096 + (unsigned)tid];
            unsigned u, d;
            u = f2u(v.x); d = u - wbase; if (d < (1u << 23)) atomicAdd(&lh[d >> 12], 1u);
            u = f2u(v.y); d = u - wbase; if (d < (1u << 23)) atomicAdd(&lh[d >> 12], 1u);
            u = f2u(v.z); d = u - wbase; if (d < (1u << 23)) atomicAdd(&lh[d >> 12], 1u);
            u = f2u(v.w); d = u - wbase; if (d < (1u << 23)) atomicAdd(&lh[d >> 12], 1u);
        }
    }
    __syncthreads();
    if (bid < SAMPB && !bad) {
        unsigned r = (unsigned)bid & (REPL - 1);
        for (int i = tid; i < NSB; i += BLK) {
            unsigned s = lh[i];
            if (s) atomicAdd(&hS2[((unsigned)i * REPL + r) * CSTR], s);
        }
    }
    gsync(bw, ++ep, nbk);                 // (2)

    unsigned hi_v = 0u, lo_v = 0u;
    {
        long long khi = (long long)ksamp - (long long)delta - (long long)aw;
        long long klo = (long long)ksamp + (long long)delta - (long long)aw;
        if (!bad) {
            if (khi <= 0) hi_v = wtop;
            else {
                scan_desc<NSB, NSB / BLK, REPL, CSTR>(hS2, (unsigned)khi, slds, sb, tid);
                if (sb[0] == SENT) bad = true;
                else hi_v = wbase + ((sb[0] + 1u) << 12);
            }
        }
        if (!bad) {
            if (klo <= 0) lo_v = wtop;
            else {
                scan_desc<NSB, NSB / BLK, REPL, CSTR>(hS2, (unsigned)klo, slds, sb, tid);
                if (sb[0] == SENT) bad = true;
                else lo_v = wbase + (sb[0] << 12);
            }
        }
        if (bad) { hi_v = 0u; lo_v = 0u; }
    }
    const unsigned band = hi_v - lo_v;    // 0 when bad or degenerate

    // ---------------- STREAM: scatter + count + stage + C1 ----------------
    if (tid == 0) sb[3] = 0u;
    __syncthreads();
    unsigned* su = lh;                    // [STAGE_CAP]
    unsigned* si = lh + STAGE_CAP;        // [STAGE_CAP]
    unsigned wcnt = 0u;
    auto classify = [&](unsigned u, float v, unsigned idxv) -> float {
        if (u >= hi_v) { ++wcnt; return v; }
        if (u - lo_v < band) {
            unsigned p = atomicAdd(&sb[3], 1u);
            if (p < STAGE_CAP) { su[p] = u; si[p] = idxv; }
            else cstore(&sc[7], 1u);
        }
        return 0.0f;
    };
    for (int i = bid * BLK + tid; i < n4; i += stride) {
        float4 v = x4[i];
        vf4 o;
        unsigned base = (unsigned)i * 4u;
        o.x = classify(f2u(v.x), v.x, base + 0u);
        o.y = classify(f2u(v.y), v.y, base + 1u);
        o.z = classify(f2u(v.z), v.z, base + 2u);
        o.w = classify(f2u(v.w), v.w, base + 3u);
        __builtin_nontemporal_store(o, (vf4*)out + i);
    }
    if (bid == 0 && tid < ntail) {
        long long idx = t0 + tid;
        float v = x[idx];
        out[idx] = classify(f2u(v), v, (unsigned)idx);
    }
    __syncthreads();
    const unsigned mycnt = (sb[3] > STAGE_CAP) ? STAGE_CAP : sb[3];
    {
        unsigned wsum = block_reduce_sum(wcnt, slds, tid);
        if (tid == 0) {
            if (wsum)  atomicAdd(&sc[0], wsum);
            if (mycnt) atomicAdd(&sc[1], mycnt);
        }
    }
    // C1: replicated channel-spread global counters of own candidates
    {
        unsigned r = (unsigned)bid & (REPL - 1);
        for (unsigned j = (unsigned)tid; j < mycnt; j += BLK)
            atomicAdd(&hC1[(((su[j] - lo_v) >> 12) * REPL + r) * CSTR], 1u);
    }
    gsync(bw, ++ep, nbk);                 // (3)

    const unsigned nhi   = cload(&sc[0]);
    const unsigned ncand = cload(&sc[1]);
    const unsigned ovf   = cload(&sc[7]);
    bool valid = (ovf == 0u) && (nhi <= k) && (k - nhi <= ncand);

    unsigned tu = 0u, needeq = 0u, ceq = 0u;
    bool skipCD = false;
    if (valid) {
        unsigned krem = k - nhi;
        if (krem == 0u) skipCD = true;
        else {
            scan_desc<NSB, NSB / BLK, REPL, CSTR>(hC1, krem, slds, sb, tid);
            if (sb[0] == SENT) valid = false;
            else {
                const unsigned bc1 = sb[0], krem2 = sb[1];
                for (unsigned j = (unsigned)tid; j < mycnt; j += BLK) {
                    unsigned d = su[j] - lo_v;
                    if ((d >> 12) == bc1) atomicAdd(&hC2[d & (NC2 - 1u)], 1u);
                }
                gsync(bw, ++ep, nbk);     // (4)
                scan_desc<NC2, NC2 / BLK, 1, 1>(hC2, krem2, slds, sb, tid);
                if (sb[0] == SENT) valid = false;
                else {
                    tu = lo_v + (bc1 << 12) + sb[0];
                    needeq = sb[1]; ceq = sb[2];
                }
            }
        }
    }

    if (valid) {
        if (!skipCD) {
            const bool allties = (needeq == ceq);
            for (unsigned j = (unsigned)tid; j < mycnt; j += BLK) {
                unsigned u = su[j];
                if (u > tu)           out[si[j]] = u2f(u);
                else if (u == tu) {
                    if (allties)      out[si[j]] = u2f(u);
                    else { unsigned q = atomicAdd(&sc[5], 1u);
                           if (q < EQ_CAP) cstore(&eq_list[q], si[j]); }
                }
            }
            if (!allties) {
                gsync(bw, ++ep, nbk);     // (5) rare
                unsigned m = cload(&sc[5]); if (m > EQ_CAP) m = EQ_CAP;
                float f = u2f(tu);
                for (unsigned j = (unsigned)tid; j < mycnt; j += BLK) {
                    if (su[j] != tu) continue;
                    unsigned idxv = si[j], cnt = 0u;
                    for (unsigned l = 0; l < m; ++l)
                        cnt += (cload(&eq_list[l]) < idxv) ? 1u : 0u;
                    if (cnt < needeq) out[idxv] = f;
                }
            }
        }
        return;
    }

    // =============== fallback: exact full 3-pass radix (rare) ===============
    // F1: 11-bit hist
    for (int i = tid; i < NSB; i += BLK) lh[i] = 0u;
    __syncthreads();
    for (int i = bid * BLK + tid; i < n4; i += stride) {
        float4 v = x4[i];
        atomicAdd(&lh[f2u(v.x) >> 21], 1u);
        atomicAdd(&lh[f2u(v.y) >> 21], 1u);
        atomicAdd(&lh[f2u(v.z) >> 21], 1u);
        atomicAdd(&lh[f2u(v.w) >> 21], 1u);
    }
    if (bid == 0 && tid < ntail) atomicAdd(&lh[f2u(x[t0 + tid]) >> 21], 1u);
    __syncthreads();
    for (int i = tid; i < NSB; i += BLK) { unsigned s = lh[i]; if (s) atomicAdd(&hF1[i], s); }
    gsync(bw, ++ep, nbk);
    scan_desc<NSB, NSB / BLK, 1, 1>(hF1, k, slds, sb, tid);
    const unsigned f1 = sb[0], kr1 = sb[1];
    __syncthreads();
    // F2: bits 20..10, filtered
    for (int i = tid; i < NSB; i += BLK) lh[i] = 0u;
    __syncthreads();
    for (int i = bid * BLK + tid; i < n4; i += stride) {
        float4 v = x4[i];
        unsigned u;
        u = f2u(v.x); if ((u >> 21) == f1) atomicAdd(&lh[(u >> 10) & 2047u], 1u);
        u = f2u(v.y); if ((u >> 21) == f1) atomicAdd(&lh[(u >> 10) & 2047u], 1u);
        u = f2u(v.z); if ((u >> 21) == f1) atomicAdd(&lh[(u >> 10) & 2047u], 1u);
        u = f2u(v.w); if ((u >> 21) == f1) atomicAdd(&lh[(u >> 10) & 2047u], 1u);
    }
    if (bid == 0 && tid < ntail) {
        unsigned u = f2u(x[t0 + tid]);
        if ((u >> 21) == f1) atomicAdd(&lh[(u >> 10) & 2047u], 1u);
    }
    __syncthreads();
    for (int i = tid; i < NSB; i += BLK) { unsigned s = lh[i]; if (s) atomicAdd(&hF2[i], s); }
    gsync(bw, ++ep, nbk);
    scan_desc<NSB, NSB / BLK, 1, 1>(hF2, kr1, slds, sb, tid);
    const unsigned f2 = sb[0], kr2 = sb[1];
    __syncthreads();
    // F3: bits 9..0, filtered
    const unsigned top22 = (f1 << 11) | f2;
    for (int i = tid; i < 1024; i += BLK) lh[i] = 0u;
    __syncthreads();
    for (int i = bid * BLK + tid; i < n4; i += stride) {
        float4 v = x4[i];
        unsigned u;
        u = f2u(v.x); if ((u >> 10) == top22) atomicAdd(&lh[u & 1023u], 1u);
        u = f2u(v.y); if ((u >> 10) == top22) atomicAdd(&lh[u & 1023u], 1u);
        u = f2u(v.z); if ((u >> 10) == top22) atomicAdd(&lh[u & 1023u], 1u);
        u = f2u(v.w); if ((u >> 10) == top22) atomicAdd(&lh[u & 1023u], 1u);
    }
    if (bid == 0 && tid < ntail) {
        unsigned u = f2u(x[t0 + tid]);
        if ((u >> 10) == top22) atomicAdd(&lh[u & 1023u], 1u);
    }
    __syncthreads();
    for (int i = tid; i < 1024; i += BLK) { unsigned s = lh[i]; if (s) atomicAdd(&hF3[i], s); }
    gsync(bw, ++ep, nbk);
    scan_desc<1024, 1024 / BLK, 1, 1>(hF3, kr2, slds, sb, tid);
    const unsigned f3 = sb[0], fneed = sb[1], fceq = sb[2];
    const unsigned ftu = (f1 << 21) | (f2 << 10) | f3;
    const bool fall = (fneed == fceq);
    // full rewrite (overwrites any junk the invalid stream wrote)
    for (int i = bid * BLK + tid; i < n4; i += stride) {
        float4 v = x4[i];
        unsigned u0 = f2u(v.x), u1 = f2u(v.y), u2 = f2u(v.z), u3 = f2u(v.w);
        vf4 o;
        o.x = (u0 > ftu || (u0 == ftu && fall)) ? v.x : 0.0f;
        o.y = (u1 > ftu || (u1 == ftu && fall)) ? v.y : 0.0f;
        o.z = (u2 > ftu || (u2 == ftu && fall)) ? v.z : 0.0f;
        o.w = (u3 > ftu || (u3 == ftu && fall)) ? v.w : 0.0f;
        __builtin_nontemporal_store(o, (vf4*)out + i);
        if (!fall && (u0 == ftu || u1 == ftu || u2 == ftu || u3 == ftu)) {
            unsigned base = (unsigned)i * 4u;
            unsigned uu[4] = { u0, u1, u2, u3 };
#pragma unroll
            for (int l = 0; l < 4; ++l)
                if (uu[l] == ftu) {
                    unsigned q = atomicAdd(&sc[5], 1u);
                    if (q < EQ_CAP) cstore(&eq_list[q], base + (unsigned)l);
                }
        }
    }
    if (bid == 0 && tid < ntail) {
        long long idx = t0 + tid;
        float v = x[idx];
        unsigned u = f2u(v);
        out[idx] = (u > ftu || (u == ftu && fall)) ? v : 0.0f;
        if (!fall && u == ftu) {
            unsigned q = atomicAdd(&sc[5], 1u);
            if (q < EQ_CAP) cstore(&eq_list[q], (unsigned)idx);
        }
    }
    if (!fall) {
        gsync(bw, ++ep, nbk);
        unsigned m = cload(&sc[5]); if (m > EQ_CAP) m = EQ_CAP;
        float f = u2f(ftu);
        for (int i = bid * BLK + tid; i < n4; i += stride) {
            float4 v = x4[i];
            unsigned base = (unsigned)i * 4u;
            unsigned uu[4] = { f2u(v.x), f2u(v.y), f2u(v.z), f2u(v.w) };
#pragma unroll
            for (int l = 0; l < 4; ++l) {
                if (uu[l] != ftu) continue;
                unsigned idxv = base + (unsigned)l, cnt = 0u;
                for (unsigned q = 0; q < m; ++q)
                    cnt += (cload(&eq_list[q]) < idxv) ? 1u : 0u;
                if (cnt < fneed) out[idxv] = f;
            }
        }
        if (bid == 0 && tid < ntail) {
            long long idx = t0 + tid;
            if (f2u(x[idx]) == ftu) {
                unsigned cnt = 0u;
                for (unsigned q = 0; q < m; ++q)
                    cnt += (cload(&eq_list[q]) < (unsigned)idx) ? 1u : 0u;
                if (cnt < fneed) out[idx] = f;
            }
        }
    }
}

extern "C" void kernel_launch(void* const* d_in, const int* in_sizes, int n_in,
                              void* d_out, int out_size, void* d_ws, size_t ws_size,
                              hipStream_t stream) {
    const float* x = (const float*)d_in[0];
    float* out = (float*)d_out;
    long long N = (long long)in_sizes[0];
    int n4 = (int)(N >> 2);
    unsigned k = (unsigned)((double)N * 0.1);
    if (k == 0u) k = 1u;

    // sampling parameters (host math only)
    unsigned nchunks = (unsigned)(n4 >> 12);              // 4096-quad chunks
    unsigned long long S_total = (unsigned long long)nchunks << 10; // elements
    unsigned ksamp = 1u;
    if (S_total > 0)
        ksamp = (unsigned)(((unsigned long long)k * S_total) / (unsigned long long)N);
    if (ksamp == 0u) ksamp = 1u;
    unsigned delta = (unsigned)(8.0 * sqrt((double)ksamp)) + 64u;

    uint8_t* w = (uint8_t*)d_ws;
    size_t cur = 0;
    unsigned* sc  = (unsigned*)(w + cur); cur += 256;
    unsigned* bw  = (unsigned*)(w + cur); cur += 12288;
    unsigned* hS1 = (unsigned*)(w + cur); cur += (size_t)NSB * REPL * CSTR * 4;  // 512 KB
    unsigned* hS2 = (unsigned*)(w + cur); cur += (size_t)NSB * REPL * CSTR * 4;  // 512 KB
    unsigned* hC1 = (unsigned*)(w + cur); cur += (size_t)NSB * REPL * CSTR * 4;  // 512 KB
    unsigned* hC2 = (unsigned*)(w + cur); cur += (size_t)NC2 * 4;                // 16 KB
    unsigned* hF1 = (unsigned*)(w + cur); cur += (size_t)NSB * 4;                // 8 KB
    unsigned* hF2 = (unsigned*)(w + cur); cur += (size_t)NSB * 4;                // 8 KB
    unsigned* hF3 = (unsigned*)(w + cur); cur += 1024 * 4;                       // 4 KB
    const size_t zbytes = cur;            // everything above gets zeroed
    unsigned* eq_list = (unsigned*)(w + cur);                                    // 256 KB

    static int g_grid = 0;
    if (g_grid == 0) {
        int nb = 0;
        if (hipOccupancyMaxActiveBlocksPerMultiprocessor(&nb, (const void*)topk_fused,
                                                         BLK, 0) != hipSuccess || nb < 1)
            nb = 4;
        int dev = 0; (void)hipGetDevice(&dev);
        int ncu = 0;
        if (hipDeviceGetAttribute(&ncu, hipDeviceAttributeMultiprocessorCount, dev) != hipSuccess || ncu < 1)
            ncu = 256;
        long long g = (long long)nb * (long long)ncu;
        if (g > MAXGRID) g = MAXGRID;
        if (g < 1) g = 1;
        g_grid = (int)g;
    }

    (void)hipMemsetAsync(w, 0, zbytes, stream);
    hipLaunchKernelGGL(topk_fused, dim3(g_grid), dim3(BLK), 0, stream,
                       x, out, N, n4, k, nchunks, ksamp, delta,
                       sc, bw, hS1, hS2, hC1, hC2, hF1, hF2, hF3, eq_list);
}